// Round 1
// baseline (2928.403 us; speedup 1.0000x reference)
//
#include <hip/hip_runtime.h>
#include <math.h>

#define BB 2
#define CIN 256
#define COUT 128
#define HH 64
#define WWD 64
#define LL 4096
#define DI 256
#define DS 16
#define DTR 8

// ---------- helpers ----------
__device__ __forceinline__ float silu_(float x){ return x / (1.f + expf(-x)); }
__device__ __forceinline__ float sigm_(float x){ return 1.f / (1.f + expf(-x)); }

// ---------- K0: W_eff[p][c][o] = sum_i w_up[c,i,p>>1,p&1] * w_fuse[i,o] ----------
__global__ void k_weff(const float* __restrict__ w_up, const float* __restrict__ w_fuse,
                       float* __restrict__ W_eff){
  int idx = blockIdx.x * 256 + threadIdx.x;   // 4*256*128 = 131072
  int o = idx & 127;
  int c = (idx >> 7) & 255;
  int p = idx >> 15;
  int kh = p >> 1, kw = p & 1;
  float acc = 0.f;
  #pragma unroll 8
  for (int i = 0; i < COUT; ++i)
    acc += w_up[((c * COUT + i) * 2 + kh) * 2 + kw] * w_fuse[i * COUT + o];
  W_eff[idx] = acc;
}

// ---------- generic transpose src(R,C) -> dst(C,R) ----------
__global__ void k_transpose(const float* __restrict__ src, float* __restrict__ dst, int R, int C){
  int idx = blockIdx.x * 256 + threadIdx.x;
  if (idx < R * C){ int r = idx / C, c = idx - r * C; dst[c * R + r] = src[idx]; }
}

// ---------- K1: fused tokens (b,l,o) ----------
__global__ void k_fused(const float* __restrict__ inp, const float* __restrict__ skip,
                        const float* __restrict__ W_eff, const float* __restrict__ w_fuse,
                        float* __restrict__ fusedT){
  // grid 512: bid = b*256 + h*4 + wt
  int bid = blockIdx.x;
  int wt = bid & 3;
  int h  = (bid >> 2) & 63;
  int b  = bid >> 8;
  int t  = threadIdx.x;          // 256
  int o  = t & 127;
  int wp = t >> 7;               // 0 or 1

  __shared__ float sIn[256 * 8];   // inp[c][wl]
  __shared__ float sSk[128 * 16];  // skip[i][wl2]
  int hi = h >> 1;
  int wi0 = wt * 8;
  #pragma unroll
  for (int k = 0; k < 8; ++k){
    int e = k * 256 + t;
    int c = e >> 3, wl = e & 7;
    sIn[e] = inp[((b * 256 + c) * 32 + hi) * 32 + wi0 + wl];
  }
  #pragma unroll
  for (int k = 0; k < 8; ++k){
    int e = k * 256 + t;
    int i = e >> 4, wl2 = e & 15;
    sSk[e] = skip[((b * 128 + i) * 64 + h) * 64 + wt * 16 + wl2];
  }
  __syncthreads();

  float acc[8];
  #pragma unroll
  for (int j = 0; j < 8; ++j) acc[j] = 0.f;

  for (int par = 0; par < 2; ++par){
    int p = (h & 1) * 2 + par;
    const float* wptr = W_eff + (size_t)p * 256 * 128 + o;
    for (int c = 0; c < 256; ++c){
      float we = wptr[c * 128];
      #pragma unroll
      for (int jj = 0; jj < 4; ++jj){
        int j = jj * 2 + par;
        int wl = (wp * 8 + j) >> 1;
        acc[j] += sIn[c * 8 + wl] * we;
      }
    }
  }
  for (int i = 0; i < 128; ++i){
    float wf = w_fuse[(128 + i) * 128 + o];
    #pragma unroll
    for (int j = 0; j < 8; ++j)
      acc[j] += sSk[i * 16 + wp * 8 + j] * wf;
  }
  #pragma unroll
  for (int j = 0; j < 8; ++j){
    int w = wt * 16 + wp * 8 + j;
    fusedT[((size_t)(b * 4096 + h * 64 + w)) * 128 + o] = acc[j];
  }
}

// ---------- instance-norm stats over l for each (b,c), token layout ----------
__global__ void k_instnorm_stats(const float* __restrict__ xt, float* __restrict__ mu,
                                 float* __restrict__ rs){
  int b = blockIdx.x >> 7, c = blockIdx.x & 127;
  const float* p = xt + (size_t)b * LL * COUT + c;
  float s = 0.f, s2 = 0.f;
  for (int l = threadIdx.x; l < LL; l += 256){
    float v = p[(size_t)l * COUT];
    s += v; s2 += v * v;
  }
  #pragma unroll
  for (int off = 32; off; off >>= 1){ s += __shfl_down(s, off); s2 += __shfl_down(s2, off); }
  __shared__ float ps[4], ps2[4];
  int w = threadIdx.x >> 6;
  if ((threadIdx.x & 63) == 0){ ps[w] = s; ps2[w] = s2; }
  __syncthreads();
  if (threadIdx.x == 0){
    float S = ps[0] + ps[1] + ps[2] + ps[3];
    float S2 = ps2[0] + ps2[1] + ps2[2] + ps2[3];
    float m = S / (float)LL;
    float var = S2 / (float)LL - m * m;
    mu[blockIdx.x] = m;
    rs[blockIdx.x] = rsqrtf(var + 1e-5f);
  }
}

// ---------- apply instnorm + leaky relu, in place ----------
__global__ void k_in_leaky(float* __restrict__ xt, const float* __restrict__ mu,
                           const float* __restrict__ rs){
  size_t idx = (size_t)blockIdx.x * 256 + threadIdx.x;
  int c = idx & 127;
  int b = (int)(idx >> 19);   // L*COUT = 524288
  float v = (xt[idx] - mu[b * 128 + c]) * rs[b * 128 + c];
  xt[idx] = v >= 0.f ? v : 0.01f * v;
}

// ---------- per-token: tok2 = x@gW_in^T ; z ; t = LN(tok2) ----------
__global__ void k_tok(const float* __restrict__ xt, const float* __restrict__ gW_inT,
                      const float* __restrict__ gW_gateT, const float* __restrict__ gb_gate,
                      const float* __restrict__ ln_g, const float* __restrict__ ln_b,
                      float* __restrict__ tok2, float* __restrict__ zb, float* __restrict__ tb){
  int tok = blockIdx.x;
  int o = threadIdx.x;   // 128
  __shared__ float sx[128];
  sx[o] = xt[(size_t)tok * 128 + o];
  __syncthreads();
  float a = 0.f, g = 0.f;
  for (int c = 0; c < 128; ++c){
    float xv = sx[c];
    a += xv * gW_inT[c * 128 + o];
    g += xv * gW_gateT[c * 128 + o];
  }
  g += gb_gate[o];
  float z = sigm_(silu_(g));
  tok2[(size_t)tok * 128 + o] = a;
  zb[(size_t)tok * 128 + o] = z;
  // layernorm over the 128 values of a
  float s = a, s2 = a * a;
  #pragma unroll
  for (int off = 32; off; off >>= 1){ s += __shfl_down(s, off); s2 += __shfl_down(s2, off); }
  __shared__ float ps[2], ps2[2];
  int w = threadIdx.x >> 6;
  if ((threadIdx.x & 63) == 0){ ps[w] = s; ps2[w] = s2; }
  __syncthreads();
  float S = ps[0] + ps[1], S2 = ps2[0] + ps2[1];
  float m = S / 128.f;
  float var = S2 / 128.f - m * m;
  tb[(size_t)tok * 128 + o] = (a - m) * rsqrtf(var + 1e-5f) * ln_g[o] + ln_b[o];
}

// ---------- xz = t @ m_Win^T ; split; silu(zm) ----------
__global__ void k_xz(const float* __restrict__ tb, const float* __restrict__ m_WinT,
                     float* __restrict__ xm, float* __restrict__ zs){
  int tok = blockIdx.x;
  int d = threadIdx.x;   // 256
  __shared__ float st[128];
  if (d < 128) st[d] = tb[(size_t)tok * 128 + d];
  __syncthreads();
  float a = 0.f, b2 = 0.f;
  for (int c = 0; c < 128; ++c){
    float tv = st[c];
    a  += tv * m_WinT[c * 512 + d];
    b2 += tv * m_WinT[c * 512 + 256 + d];
  }
  xm[(size_t)tok * 256 + d] = a;
  zs[(size_t)tok * 256 + d] = silu_(b2);
}

// ---------- causal depthwise conv + silu ----------
__global__ void k_conv(const float* __restrict__ xm, const float* __restrict__ cw,
                       const float* __restrict__ cb, float* __restrict__ xc){
  int tok = blockIdx.x;
  int b = tok >> 12;
  int l = tok & 4095;
  int d = threadIdx.x;
  float acc = cb[d];
  #pragma unroll
  for (int k = 0; k < 4; ++k){
    int ls = l - 3 + k;
    if (ls >= 0) acc += xm[((size_t)(b * 4096 + ls)) * 256 + d] * cw[d * 4 + k];
  }
  xc[(size_t)tok * 256 + d] = silu_(acc);
}

// ---------- x_dbl -> dt (softplus), Bm, Cm ----------
__global__ void k_xdbl(const float* __restrict__ xc, const float* __restrict__ m_Wx,
                       const float* __restrict__ m_Wdt, const float* __restrict__ m_bdt,
                       float* __restrict__ dtb, float* __restrict__ Bmb, float* __restrict__ Cmb){
  int tok = blockIdx.x;
  int t = threadIdx.x;   // 256
  __shared__ float sxc[256];
  __shared__ float sdbl[40];
  sxc[t] = xc[(size_t)tok * 256 + t];
  __syncthreads();
  if (t < 40){
    float a = 0.f;
    #pragma unroll 8
    for (int c = 0; c < 256; ++c) a += sxc[c] * m_Wx[t * 256 + c];
    sdbl[t] = a;
  }
  __syncthreads();
  float dtr = m_bdt[t];
  #pragma unroll
  for (int r = 0; r < 8; ++r) dtr += sdbl[r] * m_Wdt[t * 8 + r];
  float sp = (dtr > 20.f) ? dtr : log1pf(expf(dtr));
  dtb[(size_t)tok * 256 + t] = sp;
  if (t < 16)       Bmb[(size_t)tok * 16 + t]        = sdbl[8 + t];
  else if (t < 32)  Cmb[(size_t)tok * 16 + (t - 16)] = sdbl[24 + (t - 16)];
}

// ---------- selective scan; writes y_final = (scan_y + xc*D)*silu(zm) ----------
__global__ void k_scan(const float* __restrict__ dtb, const float* __restrict__ xc,
                       const float* __restrict__ Bmb, const float* __restrict__ Cmb,
                       const float* __restrict__ m_Alog, const float* __restrict__ m_D,
                       const float* __restrict__ zs, float* __restrict__ yb){
  int gid = blockIdx.x * 256 + threadIdx.x;
  int grp = gid >> 4;        // 0..511 : b*256 + d
  int s = threadIdx.x & 15;
  int b = grp >> 8;
  int d = grp & 255;
  float A = -expf(m_Alog[d * 16 + s]);
  float Dv = m_D[d];
  float h = 0.f;
  const float* dtp = dtb + (size_t)b * 4096 * 256 + d;
  const float* xcp = xc  + (size_t)b * 4096 * 256 + d;
  const float* Bp  = Bmb + (size_t)b * 4096 * 16 + s;
  const float* Cp  = Cmb + (size_t)b * 4096 * 16 + s;
  const float* zp  = zs  + (size_t)b * 4096 * 256 + d;
  float* yp        = yb  + (size_t)b * 4096 * 256 + d;
  #pragma unroll 4
  for (int l = 0; l < 4096; ++l){
    float dt  = dtp[(size_t)l * 256];
    float xcv = xcp[(size_t)l * 256];
    float Bv  = Bp[l * 16];
    float Cv  = Cp[l * 16];
    float dA = expf(dt * A);
    h = dA * h + dt * xcv * Bv;
    float p = h * Cv;
    p += __shfl_xor(p, 1, 16);
    p += __shfl_xor(p, 2, 16);
    p += __shfl_xor(p, 4, 16);
    p += __shfl_xor(p, 8, 16);
    if (s == 0){
      float zv = zp[(size_t)l * 256];
      yp[(size_t)l * 256] = (p + xcv * Dv) * zv;
    }
  }
}

// ---------- mamba out proj: mout = y @ m_Wout^T ----------
__global__ void k_mout(const float* __restrict__ yb, const float* __restrict__ m_WoutT,
                       float* __restrict__ moutb){
  int tok = blockIdx.x;
  int c = threadIdx.x;   // 128
  __shared__ float sy[256];
  sy[c] = yb[(size_t)tok * 256 + c];
  sy[c + 128] = yb[(size_t)tok * 256 + c + 128];
  __syncthreads();
  float a = 0.f;
  for (int dd = 0; dd < 256; ++dd) a += sy[dd] * m_WoutT[dd * 128 + c];
  moutb[(size_t)tok * 128 + c] = a;
}

// ---------- out_pre = x + tok2 + (mout*z)@gW_out^T ----------
__global__ void k_outpre(const float* __restrict__ tok2, const float* __restrict__ moutb,
                         const float* __restrict__ zb, const float* __restrict__ gW_outT,
                         const float* __restrict__ xt, float* __restrict__ outpre){
  int tok = blockIdx.x;
  int o = threadIdx.x;   // 128
  __shared__ float sv[128];
  sv[o] = moutb[(size_t)tok * 128 + o] * zb[(size_t)tok * 128 + o];
  __syncthreads();
  float a = 0.f;
  for (int c = 0; c < 128; ++c) a += sv[c] * gW_outT[c * 128 + o];
  size_t idx = (size_t)tok * 128 + o;
  outpre[idx] = xt[idx] + tok2[idx] + a;
}

// ---------- final: instance-norm outpre, write NCHW ----------
__global__ void k_final(const float* __restrict__ outpre, const float* __restrict__ mu,
                        const float* __restrict__ rs, float* __restrict__ out){
  size_t idx = (size_t)blockIdx.x * 256 + threadIdx.x;
  int c = idx & 127;
  size_t tok = idx >> 7;
  int l = (int)(tok & 4095);
  int b = (int)(tok >> 12);
  float v = (outpre[idx] - mu[b * 128 + c]) * rs[b * 128 + c];
  out[(size_t)(b * 128 + c) * 4096 + l] = v;
}

extern "C" void kernel_launch(void* const* d_in, const int* in_sizes, int n_in,
                              void* d_out, int out_size, void* d_ws, size_t ws_size,
                              hipStream_t stream){
  const float* inp    = (const float*)d_in[0];
  const float* skip   = (const float*)d_in[1];
  const float* w_up   = (const float*)d_in[2];
  const float* w_fuse = (const float*)d_in[3];
  const float* gW_in  = (const float*)d_in[4];
  const float* gW_gate= (const float*)d_in[5];
  const float* gb_gate= (const float*)d_in[6];
  const float* ln_g   = (const float*)d_in[7];
  const float* ln_b   = (const float*)d_in[8];
  const float* gW_out = (const float*)d_in[9];
  const float* m_Win  = (const float*)d_in[10];
  const float* m_convw= (const float*)d_in[11];
  const float* m_convb= (const float*)d_in[12];
  const float* m_Wx   = (const float*)d_in[13];
  const float* m_Wdt  = (const float*)d_in[14];
  const float* m_bdt  = (const float*)d_in[15];
  const float* m_Alog = (const float*)d_in[16];
  const float* m_D    = (const float*)d_in[17];
  const float* m_Wout = (const float*)d_in[18];
  float* out = (float*)d_out;

  float* ws = (float*)d_ws;
  float* W_eff   = ws;                      // 131072
  float* xt      = W_eff + 131072;          // 1048576 (fused tokens -> x tokens, in place)
  float* tok2    = xt + 1048576;            // 1048576
  float* zb      = tok2 + 1048576;          // 1048576
  float* tb      = zb + 1048576;            // 1048576
  float* xm      = tb + 1048576;            // 2097152
  float* zs      = xm + 2097152;            // 2097152
  float* xcb     = zs + 2097152;            // 2097152
  float* dtb     = xcb + 2097152;           // 2097152
  float* Bmb     = dtb + 2097152;           // 131072
  float* Cmb     = Bmb + 131072;            // 131072
  float* yb      = Cmb + 131072;            // 2097152
  float* moutb   = yb + 2097152;            // 1048576
  float* outpre  = moutb + 1048576;         // 1048576
  float* stats   = outpre + 1048576;        // 1024 (mu1, rs1, mu2, rs2)
  float* gW_inT  = stats + 1024;            // 16384
  float* gW_gateT= gW_inT + 16384;          // 16384
  float* gW_outT = gW_gateT + 16384;        // 16384
  float* m_WinT  = gW_outT + 16384;         // 65536
  float* m_WoutT = m_WinT + 65536;          // 32768

  float* mu1 = stats, *rs1 = stats + 256, *mu2 = stats + 512, *rs2 = stats + 768;

  // weight prep
  k_weff<<<512, 256, 0, stream>>>(w_up, w_fuse, W_eff);
  k_transpose<<<(128 * 128 + 255) / 256, 256, 0, stream>>>(gW_in, gW_inT, 128, 128);
  k_transpose<<<(128 * 128 + 255) / 256, 256, 0, stream>>>(gW_gate, gW_gateT, 128, 128);
  k_transpose<<<(128 * 128 + 255) / 256, 256, 0, stream>>>(gW_out, gW_outT, 128, 128);
  k_transpose<<<(512 * 128 + 255) / 256, 256, 0, stream>>>(m_Win, m_WinT, 512, 128);
  k_transpose<<<(128 * 256 + 255) / 256, 256, 0, stream>>>(m_Wout, m_WoutT, 128, 256);

  // upsample+fuse -> fused tokens
  k_fused<<<512, 256, 0, stream>>>(inp, skip, W_eff, w_fuse, xt);
  // instance norm 1 + leaky
  k_instnorm_stats<<<256, 256, 0, stream>>>(xt, mu1, rs1);
  k_in_leaky<<<4096, 256, 0, stream>>>(xt, mu1, rs1);
  // mixer front
  k_tok<<<8192, 128, 0, stream>>>(xt, gW_inT, gW_gateT, gb_gate, ln_g, ln_b, tok2, zb, tb);
  // mamba
  k_xz<<<8192, 256, 0, stream>>>(tb, m_WinT, xm, zs);
  k_conv<<<8192, 256, 0, stream>>>(xm, m_convw, m_convb, xcb);
  k_xdbl<<<8192, 256, 0, stream>>>(xcb, m_Wx, m_Wdt, m_bdt, dtb, Bmb, Cmb);
  k_scan<<<32, 256, 0, stream>>>(dtb, xcb, Bmb, Cmb, m_Alog, m_D, zs, yb);
  k_mout<<<8192, 128, 0, stream>>>(yb, m_WoutT, moutb);
  // mixer back + residual
  k_outpre<<<8192, 128, 0, stream>>>(tok2, moutb, zb, gW_outT, xt, outpre);
  // instance norm 2 -> NCHW output
  k_instnorm_stats<<<256, 256, 0, stream>>>(outpre, mu2, rs2);
  k_final<<<4096, 256, 0, stream>>>(outpre, mu2, rs2, out);
}

// Round 2
// 381.958 us; speedup vs baseline: 7.6668x; 7.6668x over previous
//
#include <hip/hip_runtime.h>
#include <math.h>

#define BB 2
#define CIN 256
#define COUT 128
#define HH 64
#define WWD 64
#define LL 4096
#define DI 256
#define DS 16
#define DTR 8

#define SC_T 64    // chunk length
#define SC_NC 64   // number of chunks (SC_T*SC_NC == LL)

// ---------- helpers ----------
__device__ __forceinline__ float silu_(float x){ return x / (1.f + expf(-x)); }
__device__ __forceinline__ float sigm_(float x){ return 1.f / (1.f + expf(-x)); }

// ---------- K0: W_eff[p][c][o] = sum_i w_up[c,i,p>>1,p&1] * w_fuse[i,o] ----------
__global__ void k_weff(const float* __restrict__ w_up, const float* __restrict__ w_fuse,
                       float* __restrict__ W_eff){
  int idx = blockIdx.x * 256 + threadIdx.x;   // 4*256*128 = 131072
  int o = idx & 127;
  int c = (idx >> 7) & 255;
  int p = idx >> 15;
  int kh = p >> 1, kw = p & 1;
  float acc = 0.f;
  #pragma unroll 8
  for (int i = 0; i < COUT; ++i)
    acc += w_up[((c * COUT + i) * 2 + kh) * 2 + kw] * w_fuse[i * COUT + o];
  W_eff[idx] = acc;
}

// ---------- generic transpose src(R,C) -> dst(C,R) ----------
__global__ void k_transpose(const float* __restrict__ src, float* __restrict__ dst, int R, int C){
  int idx = blockIdx.x * 256 + threadIdx.x;
  if (idx < R * C){ int r = idx / C, c = idx - r * C; dst[c * R + r] = src[idx]; }
}

// ---------- K1: fused tokens (b,l,o) ----------
__global__ void k_fused(const float* __restrict__ inp, const float* __restrict__ skip,
                        const float* __restrict__ W_eff, const float* __restrict__ w_fuse,
                        float* __restrict__ fusedT){
  // grid 512: bid = b*256 + h*4 + wt
  int bid = blockIdx.x;
  int wt = bid & 3;
  int h  = (bid >> 2) & 63;
  int b  = bid >> 8;
  int t  = threadIdx.x;          // 256
  int o  = t & 127;
  int wp = t >> 7;               // 0 or 1

  __shared__ float sIn[256 * 8];   // inp[c][wl]
  __shared__ float sSk[128 * 16];  // skip[i][wl2]
  int hi = h >> 1;
  int wi0 = wt * 8;
  #pragma unroll
  for (int k = 0; k < 8; ++k){
    int e = k * 256 + t;
    int c = e >> 3, wl = e & 7;
    sIn[e] = inp[((b * 256 + c) * 32 + hi) * 32 + wi0 + wl];
  }
  #pragma unroll
  for (int k = 0; k < 8; ++k){
    int e = k * 256 + t;
    int i = e >> 4, wl2 = e & 15;
    sSk[e] = skip[((b * 128 + i) * 64 + h) * 64 + wt * 16 + wl2];
  }
  __syncthreads();

  float acc[8];
  #pragma unroll
  for (int j = 0; j < 8; ++j) acc[j] = 0.f;

  for (int par = 0; par < 2; ++par){
    int p = (h & 1) * 2 + par;
    const float* wptr = W_eff + (size_t)p * 256 * 128 + o;
    for (int c = 0; c < 256; ++c){
      float we = wptr[c * 128];
      #pragma unroll
      for (int jj = 0; jj < 4; ++jj){
        int j = jj * 2 + par;
        int wl = (wp * 8 + j) >> 1;
        acc[j] += sIn[c * 8 + wl] * we;
      }
    }
  }
  for (int i = 0; i < 128; ++i){
    float wf = w_fuse[(128 + i) * 128 + o];
    #pragma unroll
    for (int j = 0; j < 8; ++j)
      acc[j] += sSk[i * 16 + wp * 8 + j] * wf;
  }
  #pragma unroll
  for (int j = 0; j < 8; ++j){
    int w = wt * 16 + wp * 8 + j;
    fusedT[((size_t)(b * 4096 + h * 64 + w)) * 128 + o] = acc[j];
  }
}

// ---------- instance-norm stats over l for each (b,c), token layout ----------
__global__ void k_instnorm_stats(const float* __restrict__ xt, float* __restrict__ mu,
                                 float* __restrict__ rs){
  int b = blockIdx.x >> 7, c = blockIdx.x & 127;
  const float* p = xt + (size_t)b * LL * COUT + c;
  float s = 0.f, s2 = 0.f;
  for (int l = threadIdx.x; l < LL; l += 256){
    float v = p[(size_t)l * COUT];
    s += v; s2 += v * v;
  }
  #pragma unroll
  for (int off = 32; off; off >>= 1){ s += __shfl_down(s, off); s2 += __shfl_down(s2, off); }
  __shared__ float ps[4], ps2[4];
  int w = threadIdx.x >> 6;
  if ((threadIdx.x & 63) == 0){ ps[w] = s; ps2[w] = s2; }
  __syncthreads();
  if (threadIdx.x == 0){
    float S = ps[0] + ps[1] + ps[2] + ps[3];
    float S2 = ps2[0] + ps2[1] + ps2[2] + ps2[3];
    float m = S / (float)LL;
    float var = S2 / (float)LL - m * m;
    mu[blockIdx.x] = m;
    rs[blockIdx.x] = rsqrtf(var + 1e-5f);
  }
}

// ---------- apply instnorm + leaky relu, in place ----------
__global__ void k_in_leaky(float* __restrict__ xt, const float* __restrict__ mu,
                           const float* __restrict__ rs){
  size_t idx = (size_t)blockIdx.x * 256 + threadIdx.x;
  int c = idx & 127;
  int b = (int)(idx >> 19);   // L*COUT = 524288
  float v = (xt[idx] - mu[b * 128 + c]) * rs[b * 128 + c];
  xt[idx] = v >= 0.f ? v : 0.01f * v;
}

// ---------- per-token: tok2 = x@gW_in^T ; z ; t = LN(tok2) ----------
__global__ void k_tok(const float* __restrict__ xt, const float* __restrict__ gW_inT,
                      const float* __restrict__ gW_gateT, const float* __restrict__ gb_gate,
                      const float* __restrict__ ln_g, const float* __restrict__ ln_b,
                      float* __restrict__ tok2, float* __restrict__ zb, float* __restrict__ tb){
  int tok = blockIdx.x;
  int o = threadIdx.x;   // 128
  __shared__ float sx[128];
  sx[o] = xt[(size_t)tok * 128 + o];
  __syncthreads();
  float a = 0.f, g = 0.f;
  for (int c = 0; c < 128; ++c){
    float xv = sx[c];
    a += xv * gW_inT[c * 128 + o];
    g += xv * gW_gateT[c * 128 + o];
  }
  g += gb_gate[o];
  float z = sigm_(silu_(g));
  tok2[(size_t)tok * 128 + o] = a;
  zb[(size_t)tok * 128 + o] = z;
  // layernorm over the 128 values of a
  float s = a, s2 = a * a;
  #pragma unroll
  for (int off = 32; off; off >>= 1){ s += __shfl_down(s, off); s2 += __shfl_down(s2, off); }
  __shared__ float ps[2], ps2[2];
  int w = threadIdx.x >> 6;
  if ((threadIdx.x & 63) == 0){ ps[w] = s; ps2[w] = s2; }
  __syncthreads();
  float S = ps[0] + ps[1], S2 = ps2[0] + ps2[1];
  float m = S / 128.f;
  float var = S2 / 128.f - m * m;
  tb[(size_t)tok * 128 + o] = (a - m) * rsqrtf(var + 1e-5f) * ln_g[o] + ln_b[o];
}

// ---------- xz = t @ m_Win^T ; split; silu(zm) ----------
__global__ void k_xz(const float* __restrict__ tb, const float* __restrict__ m_WinT,
                     float* __restrict__ xm, float* __restrict__ zs){
  int tok = blockIdx.x;
  int d = threadIdx.x;   // 256
  __shared__ float st[128];
  if (d < 128) st[d] = tb[(size_t)tok * 128 + d];
  __syncthreads();
  float a = 0.f, b2 = 0.f;
  for (int c = 0; c < 128; ++c){
    float tv = st[c];
    a  += tv * m_WinT[c * 512 + d];
    b2 += tv * m_WinT[c * 512 + 256 + d];
  }
  xm[(size_t)tok * 256 + d] = a;
  zs[(size_t)tok * 256 + d] = silu_(b2);
}

// ---------- causal depthwise conv + silu ----------
__global__ void k_conv(const float* __restrict__ xm, const float* __restrict__ cw,
                       const float* __restrict__ cb, float* __restrict__ xc){
  int tok = blockIdx.x;
  int b = tok >> 12;
  int l = tok & 4095;
  int d = threadIdx.x;
  float acc = cb[d];
  #pragma unroll
  for (int k = 0; k < 4; ++k){
    int ls = l - 3 + k;
    if (ls >= 0) acc += xm[((size_t)(b * 4096 + ls)) * 256 + d] * cw[d * 4 + k];
  }
  xc[(size_t)tok * 256 + d] = silu_(acc);
}

// ---------- x_dbl -> dt (softplus), Bm, Cm ----------
__global__ void k_xdbl(const float* __restrict__ xc, const float* __restrict__ m_Wx,
                       const float* __restrict__ m_Wdt, const float* __restrict__ m_bdt,
                       float* __restrict__ dtb, float* __restrict__ Bmb, float* __restrict__ Cmb){
  int tok = blockIdx.x;
  int t = threadIdx.x;   // 256
  __shared__ float sxc[256];
  __shared__ float sdbl[40];
  sxc[t] = xc[(size_t)tok * 256 + t];
  __syncthreads();
  if (t < 40){
    float a = 0.f;
    #pragma unroll 8
    for (int c = 0; c < 256; ++c) a += sxc[c] * m_Wx[t * 256 + c];
    sdbl[t] = a;
  }
  __syncthreads();
  float dtr = m_bdt[t];
  #pragma unroll
  for (int r = 0; r < 8; ++r) dtr += sdbl[r] * m_Wdt[t * 8 + r];
  float sp = (dtr > 20.f) ? dtr : log1pf(expf(dtr));
  dtb[(size_t)tok * 256 + t] = sp;
  if (t < 16)       Bmb[(size_t)tok * 16 + t]        = sdbl[8 + t];
  else if (t < 32)  Cmb[(size_t)tok * 16 + (t - 16)] = sdbl[24 + (t - 16)];
}

// ---------- chunked scan, pass A: local scan per chunk (h0=0) + decay product ----------
__global__ void k_scanA(const float* __restrict__ dtb, const float* __restrict__ xc,
                        const float* __restrict__ Bmb, const float* __restrict__ m_Alog,
                        float* __restrict__ chunkA, float* __restrict__ chunkH){
  int gid = blockIdx.x * 256 + threadIdx.x;   // 2*64*256*16 = 524288
  int s = gid & 15;
  int d = (gid >> 4) & 255;
  int c = (gid >> 12) & 63;
  int b = gid >> 18;
  float A = -expf(m_Alog[d * 16 + s]);
  int l0 = c * SC_T;
  const float* dtp = dtb + ((size_t)(b * LL + l0)) * 256 + d;
  const float* xcp = xc  + ((size_t)(b * LL + l0)) * 256 + d;
  const float* Bp  = Bmb + ((size_t)(b * LL + l0)) * 16 + s;
  float h = 0.f, aprod = 1.f;
  #pragma unroll 4
  for (int l = 0; l < SC_T; ++l){
    float dt  = dtp[l * 256];
    float xcv = xcp[l * 256];
    float Bv  = Bp[l * 16];
    float dA = expf(dt * A);
    aprod *= dA;
    h = dA * h + dt * xcv * Bv;
  }
  size_t idx = ((size_t)(b * SC_NC + c)) * 4096 + d * 16 + s;
  chunkA[idx] = aprod;
  chunkH[idx] = h;
}

// ---------- chunked scan, pass B: serial combine over chunks; store carry at chunk start ----------
__global__ void k_scanB(const float* __restrict__ chunkA, const float* __restrict__ chunkH,
                        float* __restrict__ carryBuf){
  int gid = blockIdx.x * 256 + threadIdx.x;  // 8192
  int ds = gid & 4095;   // d*16+s
  int b = gid >> 12;
  float carry = 0.f;
  #pragma unroll 4
  for (int c = 0; c < SC_NC; ++c){
    size_t idx = ((size_t)(b * SC_NC + c)) * 4096 + ds;
    carryBuf[idx] = carry;
    carry = chunkA[idx] * carry + chunkH[idx];
  }
}

// ---------- chunked scan, pass C: re-scan with carry, reduce over s, fuse +xc*D and *silu(zm) ----------
__global__ void k_scanC(const float* __restrict__ dtb, const float* __restrict__ xc,
                        const float* __restrict__ Bmb, const float* __restrict__ Cmb,
                        const float* __restrict__ m_Alog, const float* __restrict__ m_D,
                        const float* __restrict__ zs, const float* __restrict__ carryBuf,
                        float* __restrict__ yb){
  int gid = blockIdx.x * 256 + threadIdx.x;   // 524288
  int s = gid & 15;
  int d = (gid >> 4) & 255;
  int c = (gid >> 12) & 63;
  int b = gid >> 18;
  float A = -expf(m_Alog[d * 16 + s]);
  float Dv = m_D[d];
  int l0 = c * SC_T;
  const float* dtp = dtb + ((size_t)(b * LL + l0)) * 256 + d;
  const float* xcp = xc  + ((size_t)(b * LL + l0)) * 256 + d;
  const float* Bp  = Bmb + ((size_t)(b * LL + l0)) * 16 + s;
  const float* Cp  = Cmb + ((size_t)(b * LL + l0)) * 16 + s;
  const float* zp  = zs  + ((size_t)(b * LL + l0)) * 256 + d;
  float* yp        = yb  + ((size_t)(b * LL + l0)) * 256 + d;
  float h = carryBuf[((size_t)(b * SC_NC + c)) * 4096 + d * 16 + s];
  #pragma unroll 2
  for (int l = 0; l < SC_T; ++l){
    float dt  = dtp[l * 256];
    float xcv = xcp[l * 256];
    float Bv  = Bp[l * 16];
    float Cv  = Cp[l * 16];
    float dA = expf(dt * A);
    h = dA * h + dt * xcv * Bv;
    float p = h * Cv;
    p += __shfl_xor(p, 1, 16);
    p += __shfl_xor(p, 2, 16);
    p += __shfl_xor(p, 4, 16);
    p += __shfl_xor(p, 8, 16);
    if (s == 0){
      float zv = zp[(size_t)l * 256];
      yp[(size_t)l * 256] = (p + xcv * Dv) * zv;
    }
  }
}

// ---------- mamba out proj: mout = y @ m_Wout^T ----------
__global__ void k_mout(const float* __restrict__ yb, const float* __restrict__ m_WoutT,
                       float* __restrict__ moutb){
  int tok = blockIdx.x;
  int c = threadIdx.x;   // 128
  __shared__ float sy[256];
  sy[c] = yb[(size_t)tok * 256 + c];
  sy[c + 128] = yb[(size_t)tok * 256 + c + 128];
  __syncthreads();
  float a = 0.f;
  for (int dd = 0; dd < 256; ++dd) a += sy[dd] * m_WoutT[dd * 128 + c];
  moutb[(size_t)tok * 128 + c] = a;
}

// ---------- out_pre = x + tok2 + (mout*z)@gW_out^T ----------
__global__ void k_outpre(const float* __restrict__ tok2, const float* __restrict__ moutb,
                         const float* __restrict__ zb, const float* __restrict__ gW_outT,
                         const float* __restrict__ xt, float* __restrict__ outpre){
  int tok = blockIdx.x;
  int o = threadIdx.x;   // 128
  __shared__ float sv[128];
  sv[o] = moutb[(size_t)tok * 128 + o] * zb[(size_t)tok * 128 + o];
  __syncthreads();
  float a = 0.f;
  for (int c = 0; c < 128; ++c) a += sv[c] * gW_outT[c * 128 + o];
  size_t idx = (size_t)tok * 128 + o;
  outpre[idx] = xt[idx] + tok2[idx] + a;
}

// ---------- final: instance-norm outpre, write NCHW ----------
__global__ void k_final(const float* __restrict__ outpre, const float* __restrict__ mu,
                        const float* __restrict__ rs, float* __restrict__ out){
  size_t idx = (size_t)blockIdx.x * 256 + threadIdx.x;
  int c = idx & 127;
  size_t tok = idx >> 7;
  int l = (int)(tok & 4095);
  int b = (int)(tok >> 12);
  float v = (outpre[idx] - mu[b * 128 + c]) * rs[b * 128 + c];
  out[(size_t)(b * 128 + c) * 4096 + l] = v;
}

extern "C" void kernel_launch(void* const* d_in, const int* in_sizes, int n_in,
                              void* d_out, int out_size, void* d_ws, size_t ws_size,
                              hipStream_t stream){
  const float* inp    = (const float*)d_in[0];
  const float* skip   = (const float*)d_in[1];
  const float* w_up   = (const float*)d_in[2];
  const float* w_fuse = (const float*)d_in[3];
  const float* gW_in  = (const float*)d_in[4];
  const float* gW_gate= (const float*)d_in[5];
  const float* gb_gate= (const float*)d_in[6];
  const float* ln_g   = (const float*)d_in[7];
  const float* ln_b   = (const float*)d_in[8];
  const float* gW_out = (const float*)d_in[9];
  const float* m_Win  = (const float*)d_in[10];
  const float* m_convw= (const float*)d_in[11];
  const float* m_convb= (const float*)d_in[12];
  const float* m_Wx   = (const float*)d_in[13];
  const float* m_Wdt  = (const float*)d_in[14];
  const float* m_bdt  = (const float*)d_in[15];
  const float* m_Alog = (const float*)d_in[16];
  const float* m_D    = (const float*)d_in[17];
  const float* m_Wout = (const float*)d_in[18];
  float* out = (float*)d_out;

  float* ws = (float*)d_ws;
  float* W_eff   = ws;                      // 131072
  float* xt      = W_eff + 131072;          // 1048576
  float* tok2    = xt + 1048576;            // 1048576
  float* zb      = tok2 + 1048576;          // 1048576
  float* tb      = zb + 1048576;            // 1048576
  float* xm      = tb + 1048576;            // 2097152
  float* zs      = xm + 2097152;            // 2097152
  float* xcb     = zs + 2097152;            // 2097152
  float* dtb     = xcb + 2097152;           // 2097152
  float* Bmb     = dtb + 2097152;           // 131072
  float* Cmb     = Bmb + 131072;            // 131072
  float* yb      = Cmb + 131072;            // 2097152
  float* moutb   = yb + 2097152;            // 1048576
  float* outpre  = moutb + 1048576;         // 1048576
  float* stats   = outpre + 1048576;        // 1024 (mu1, rs1, mu2, rs2)
  float* gW_inT  = stats + 1024;            // 16384
  float* gW_gateT= gW_inT + 16384;          // 16384
  float* gW_outT = gW_gateT + 16384;        // 16384
  float* m_WinT  = gW_outT + 16384;         // 65536
  float* m_WoutT = m_WinT + 65536;          // 32768
  float* chunkA  = m_WoutT + 32768;         // 524288
  float* chunkH  = chunkA + 524288;         // 524288
  float* carryBuf= chunkH + 524288;         // 524288

  float* mu1 = stats, *rs1 = stats + 256, *mu2 = stats + 512, *rs2 = stats + 768;

  // weight prep
  k_weff<<<512, 256, 0, stream>>>(w_up, w_fuse, W_eff);
  k_transpose<<<(128 * 128 + 255) / 256, 256, 0, stream>>>(gW_in, gW_inT, 128, 128);
  k_transpose<<<(128 * 128 + 255) / 256, 256, 0, stream>>>(gW_gate, gW_gateT, 128, 128);
  k_transpose<<<(128 * 128 + 255) / 256, 256, 0, stream>>>(gW_out, gW_outT, 128, 128);
  k_transpose<<<(512 * 128 + 255) / 256, 256, 0, stream>>>(m_Win, m_WinT, 512, 128);
  k_transpose<<<(128 * 256 + 255) / 256, 256, 0, stream>>>(m_Wout, m_WoutT, 128, 256);

  // upsample+fuse -> fused tokens
  k_fused<<<512, 256, 0, stream>>>(inp, skip, W_eff, w_fuse, xt);
  // instance norm 1 + leaky
  k_instnorm_stats<<<256, 256, 0, stream>>>(xt, mu1, rs1);
  k_in_leaky<<<4096, 256, 0, stream>>>(xt, mu1, rs1);
  // mixer front
  k_tok<<<8192, 128, 0, stream>>>(xt, gW_inT, gW_gateT, gb_gate, ln_g, ln_b, tok2, zb, tb);
  // mamba
  k_xz<<<8192, 256, 0, stream>>>(tb, m_WinT, xm, zs);
  k_conv<<<8192, 256, 0, stream>>>(xm, m_convw, m_convb, xcb);
  k_xdbl<<<8192, 256, 0, stream>>>(xcb, m_Wx, m_Wdt, m_bdt, dtb, Bmb, Cmb);
  // chunked parallel scan
  k_scanA<<<2048, 256, 0, stream>>>(dtb, xcb, Bmb, m_Alog, chunkA, chunkH);
  k_scanB<<<32, 256, 0, stream>>>(chunkA, chunkH, carryBuf);
  k_scanC<<<2048, 256, 0, stream>>>(dtb, xcb, Bmb, Cmb, m_Alog, m_D, zs, carryBuf, yb);
  k_mout<<<8192, 128, 0, stream>>>(yb, m_WoutT, moutb);
  // mixer back + residual
  k_outpre<<<8192, 128, 0, stream>>>(tok2, moutb, zb, gW_outT, xt, outpre);
  // instance norm 2 -> NCHW output
  k_instnorm_stats<<<256, 256, 0, stream>>>(outpre, mu2, rs2);
  k_final<<<4096, 256, 0, stream>>>(outpre, mu2, rs2, out);
}